// Round 1
// 1467.421 us; speedup vs baseline: 1.1137x; 1.1137x over previous
//
#include <hip/hip_runtime.h>

// ---------------------------------------------------------------------------
// FutureCameraHead on MI355X (gfx950)
// Trunk (2 ResConvBlocks = 6x [131424,512]@[512,512]) in bf16 MFMA.
// This rev: 2-phase double-buffered K-loop (stage t+1 || compute t, ONE
// vmcnt(0)+barrier per K-step) + LDS-staged epilogue for coalesced 16B/lane
// bf16 stores (fixes the 1.67x WRITE_SIZE amplification of the fragment-
// layout scalar stores). Tail (rows<=192) in fp32. 3x3 SVD via fp64 Jacobi.
// ---------------------------------------------------------------------------

typedef unsigned short u16;
typedef __attribute__((ext_vector_type(8))) short short8;   // 8 x bf16 (4 VGPRs)
typedef __attribute__((ext_vector_type(4))) float f32x4;    // MFMA acc

constexpr int  DDIM    = 512;
constexpr long R_ROWS  = 96L * 1369L;   // 131424 (BN * hw)
constexpr long R_PAD   = 1027L * 128L;  // 131456 buffer rows (multiple of 128)
constexpr int  RT_GRID = 1032;          // row tiles in remap space (8*129): 20 idle blocks

__device__ __forceinline__ u16 f2b(float f) {  // fp32 -> bf16 RNE
  union { float f; unsigned u; } x; x.f = f;
  unsigned r = (x.u + 0x7FFFu + ((x.u >> 16) & 1u)) >> 16;
  return (u16)r;
}
__device__ __forceinline__ float b2f(u16 b) {
  union { unsigned u; float f; } x; x.u = ((unsigned)b) << 16;
  return x.f;
}

// Epilogue LDS swizzle: bank-even for both the fragment-layout scalar writes
// and the row-linear float4 readback. Bijective per row (XOR bits 2-4 only,
// so 4-aligned blocks stay contiguous for float4 reads).
__device__ __forceinline__ int csw(int row, int col) {
  return col ^ (((col >> 5) & 3) << 2) ^ (((row >> 2) & 1) << 4);
}

// --- feat fp32 -> bf16 padded buffer (pad rows zeroed) ----------------------
__global__ void convert_feat_k(const float* __restrict__ in, u16* __restrict__ out) {
  long i4 = ((long)blockIdx.x * 256 + threadIdx.x) * 4;
  if (i4 >= R_PAD * DDIM) return;
  ushort4 o;
  if (i4 < R_ROWS * DDIM) {
    float4 v = *(const float4*)(in + i4);
    o.x = f2b(v.x); o.y = f2b(v.y); o.z = f2b(v.z); o.w = f2b(v.w);
  } else {
    o.x = 0; o.y = 0; o.z = 0; o.w = 0;
  }
  *(ushort4*)(out + i4) = o;
}

// --- W_res [6][K=512][N=512] fp32 -> Wt [6][N][K] bf16 ----------------------
__global__ void transpose_w_k(const float* __restrict__ W, u16* __restrict__ Wt) {
  int idx = blockIdx.x * 256 + threadIdx.x;
  if (idx >= 6 * 512 * 512) return;
  int g = idx >> 18, rem = idx & 262143;
  int n = rem >> 9, k = rem & 511;
  Wt[idx] = f2b(W[(long)g * 262144 + (long)k * 512 + n]);
}

// --- bf16 GEMM: Y[r][c] = act(X[r,:] @ W[:,c] + bias[c]) --------------------
// X: [R_PAD][512] bf16, Wt: [512(N)][512(K)] bf16 (W transposed)
// K-loop LDS layout: 16B chunk (r,c) lives at chunk index r*8 + (c ^ (r&7))
// (XOR swizzle -> conflict-free ds_read_b128).
// 2-phase schedule: prologue stages tile0; each iter stages tile t+1, computes
// tile t, then a single __syncthreads (vmcnt(0)+lgkmcnt(0)+barrier) per iter.
// Epilogue: fp32 tile staged in LDS (aliasing the now-dead A/B buffers), then
// coalesced short8 stores with vectorized residual add.
// MODE 0: Y = bf16(relu(y));  MODE 1: Y = bf16(b2f(Res) + relu(y))
template <int MODE>
__global__ __launch_bounds__(256, 2)
void gemm_k(const u16* __restrict__ X, const u16* __restrict__ Wt,
            const float* __restrict__ bias, const u16* Res, u16* Y) {
  __shared__ __align__(16) char smem[65536];           // 64 KB: dbuf A/B, then fp32 C
  u16 (*lA)[128 * 64] = reinterpret_cast<u16(*)[128 * 64]>(smem);           // [2][8192]
  u16 (*lB)[128 * 64] = reinterpret_cast<u16(*)[128 * 64]>(smem + 32768);   // [2][8192]
  float* lC = reinterpret_cast<float*>(smem);                               // [128*128]

  const int tid  = threadIdx.x;
  const int lane = tid & 63;
  const int wv   = tid >> 6;
  const int wm   = wv & 1;       // wave row (2x2 wave grid -> 64x64 each)
  const int wn   = wv >> 1;
  const int l15  = lane & 15;
  const int quad = lane >> 4;

  // XCD-aware remap: 32-block windows; all 4 col-tiles of a row tile share
  // b%8 (-> same XCD under round-robin dispatch) for L2 reuse of X.
  const int b   = blockIdx.x;          // [0, 4128)
  const int win = b >> 5, i32 = b & 31;
  const int rt  = win * 8 + (i32 & 7);
  const int ct  = i32 >> 3;
  if (rt >= 1027) return;              // 20 idle blocks (RT_GRID pad)
  const int  colBase = ct * 128;
  const long rowBase = (long)rt * 128;

  f32x4 acc[4][4];
#pragma unroll
  for (int i = 0; i < 4; ++i)
#pragma unroll
    for (int j = 0; j < 4; ++j) acc[i][j] = (f32x4){0.f, 0.f, 0.f, 0.f};

  // stage 128x64 of X and Wt into buffer p; LDS dest is lane-contiguous
  // (required by global_load_lds); global source column is XOR-permuted per row.
  auto STAGE = [&](int p, int k0) {
#pragma unroll
    for (int j = 0; j < 4; ++j) {
      int L = tid + 256 * j;            // LDS chunk index 0..1023
      int r = L >> 3, cS = L & 7;
      int c = cS ^ (r & 7);             // global chunk this LDS slot holds
      const u16* ga = X + (rowBase + r) * DDIM + (k0 + c * 8);
      __builtin_amdgcn_global_load_lds(
          (const __attribute__((address_space(1))) void*)ga,
          (__attribute__((address_space(3))) void*)&lA[p][L * 8], 16, 0, 0);
      const u16* gb = Wt + (long)(colBase + r) * DDIM + (k0 + c * 8);
      __builtin_amdgcn_global_load_lds(
          (const __attribute__((address_space(1))) void*)gb,
          (__attribute__((address_space(3))) void*)&lB[p][L * 8], 16, 0, 0);
    }
  };

  STAGE(0, 0);
  __syncthreads();                     // prologue drain (one-time)

  int p = 0;
  for (int t = 0; t < 8; ++t) {        // 8 K-steps of 64
    if (t < 7) STAGE(p ^ 1, (t + 1) * 64);   // prefetch next tile (in flight
                                             // across the whole compute phase)
#pragma unroll
    for (int kk = 0; kk < 2; ++kk) {
      const int cx = (((kk * 4 + quad) ^ (l15 & 7))) * 8;  // swizzled k-chunk
      short8 af[4], bfr[4];
#pragma unroll
      for (int i = 0; i < 4; ++i)
        af[i] = *(const short8*)&lA[p][(wm * 64 + i * 16 + l15) * 64 + cx];
#pragma unroll
      for (int j = 0; j < 4; ++j)
        bfr[j] = *(const short8*)&lB[p][(wn * 64 + j * 16 + l15) * 64 + cx];
#pragma unroll
      for (int i = 0; i < 4; ++i)
#pragma unroll
        for (int j = 0; j < 4; ++j)
          acc[i][j] = __builtin_amdgcn_mfma_f32_16x16x32_bf16(af[i], bfr[j], acc[i][j], 0, 0, 0);
    }
    __syncthreads();   // vmcnt(0): next tile landed; lgkmcnt(0): ds_reads done
    p ^= 1;
  }

  // ---- epilogue pass 1: bias+relu -> fp32 tile in LDS (C layout: col=lane&15,
  // row=quad*4+reg; m89-verified). Swizzled for bank-even scalar writes.
#pragma unroll
  for (int j = 0; j < 4; ++j) {
    int colj = wn * 64 + j * 16 + l15;
    float bv = bias[colBase + colj];
#pragma unroll
    for (int i = 0; i < 4; ++i) {
      int row0 = wm * 64 + i * 16 + quad * 4;
#pragma unroll
      for (int r = 0; r < 4; ++r) {
        int row = row0 + r;
        lC[row * 128 + csw(row, colj)] = fmaxf(acc[i][j][r] + bv, 0.f);
      }
    }
  }
  __syncthreads();

  // ---- epilogue pass 2: coalesced 16B/lane bf16 stores (+ vectorized residual)
#pragma unroll
  for (int it = 0; it < 8; ++it) {
    int idx = it * 256 + tid;          // 8-col chunk id, 0..2047
    int row = idx >> 4;                // 0..127
    int c8  = (idx & 15) * 8;          // 0..120
    float v[8];
    *(float4*)&v[0] = *(const float4*)&lC[row * 128 + csw(row, c8)];
    *(float4*)&v[4] = *(const float4*)&lC[row * 128 + csw(row, c8 + 4)];
    long gidx = (rowBase + row) * DDIM + colBase + c8;
    if (MODE == 1) {
      short8 rv = *(const short8*)&Res[gidx];
#pragma unroll
      for (int k = 0; k < 8; ++k) v[k] += b2f((u16)rv[k]);
    }
    short8 o;
#pragma unroll
    for (int k = 0; k < 8; ++k) o[k] = (short)f2b(v[k]);
    *(short8*)&Y[gidx] = o;
  }
}

// --- pooling: pooled[bn][d] = mean_p feat[bn*1369+p][d] ---------------------
__global__ void zero_k(float* p, int n) {
  int i = blockIdx.x * 256 + threadIdx.x;
  if (i < n) p[i] = 0.f;
}

__global__ void pool_k(const u16* __restrict__ feat, float* __restrict__ pooled) {
  int bn = blockIdx.x, ch = blockIdx.y, d = threadIdx.x;  // block 512
  int p0 = ch * 172, p1 = p0 + 172;
  if (p1 > 1369) p1 = 1369;
  float s = 0.f;
  long base = ((long)bn * 1369 + p0) * DDIM + d;
  for (int p = p0; p < p1; ++p) { s += b2f(feat[base]); base += DDIM; }
  atomicAdd(&pooled[bn * DDIM + d], s * (1.0f / 1369.0f));
}

__global__ void gctx_k(const float* __restrict__ pooled, float* __restrict__ gctx) {
  int i = blockIdx.x * 256 + threadIdx.x;  // 32*512
  if (i >= 32 * DDIM) return;
  int b = i >> 9, d = i & 511;
  const float* p = pooled + (long)b * 3 * DDIM + d;
  gctx[i] = (p[0] + p[DDIM] + p[2 * DDIM]) * (1.0f / 3.0f);
}

// --- small fp32 linear: out[r][n] = act(in[r,:] @ W[:,n] + b[n]) ------------
template <bool RELU>
__global__ void lin_k(const float* __restrict__ in, const float* __restrict__ W,
                      const float* __restrict__ bias, float* __restrict__ out,
                      int K, int N) {
  int n = blockIdx.x * 256 + threadIdx.x;
  int r = blockIdx.y;
  if (n >= N) return;
  float acc = bias[n];
  const float* xi = in + (long)r * K;
#pragma unroll 8
  for (int k = 0; k < K; ++k) acc = fmaf(xi[k], W[(long)k * N + n], acc);
  if (RELU) acc = fmaxf(acc, 0.f);
  out[(long)r * N + n] = acc;
}

// --- pose head: 12 dots + fp64 Jacobi SVD orthogonalize + 4x4 assemble ------
__global__ void pose_k(const float* __restrict__ h,
                       const float* __restrict__ Wt, const float* __restrict__ bt,
                       const float* __restrict__ Wr, const float* __restrict__ br,
                       float* __restrict__ out) {
  int row = blockIdx.x;
  int lane = threadIdx.x;  // 64
  const float* hr = h + (long)row * DDIM;
  float part[12];
#pragma unroll
  for (int c = 0; c < 12; ++c) {
    float acc = 0.f;
    for (int k = lane; k < DDIM; k += 64) {
      float wvv = (c < 3) ? Wt[k * 3 + c] : Wr[k * 9 + (c - 3)];
      acc += hr[k] * wvv;
    }
#pragma unroll
    for (int off = 32; off > 0; off >>= 1) acc += __shfl_down(acc, off);
    part[c] = acc;
  }
  if (lane != 0) return;

  double t3[3];
  for (int i = 0; i < 3; ++i) t3[i] = (double)part[i] + (double)bt[i];
  double m[3][3];
  for (int i = 0; i < 3; ++i)
    for (int j = 0; j < 3; ++j) m[i][j] = (double)part[3 + i * 3 + j] + (double)br[i * 3 + j];
  for (int i = 0; i < 3; ++i) {
    double nn = sqrt(m[i][0] * m[i][0] + m[i][1] * m[i][1] + m[i][2] * m[i][2]);
    if (nn < 1e-12) nn = 1e-12;
    m[i][0] /= nn; m[i][1] /= nn; m[i][2] /= nn;
  }
  double Km[3][3];
  for (int a = 0; a < 3; ++a)
    for (int b = 0; b < 3; ++b) {
      double s = 0;
      for (int i = 0; i < 3; ++i) s += m[i][a] * m[i][b];
      Km[a][b] = s;
    }
  double V[3][3] = {{1, 0, 0}, {0, 1, 0}, {0, 0, 1}};
  const int PQ[3][2] = {{0, 1}, {0, 2}, {1, 2}};
  for (int sweep = 0; sweep < 20; ++sweep) {
    for (int e = 0; e < 3; ++e) {
      int p = PQ[e][0], q = PQ[e][1];
      double apq = Km[p][q];
      if (apq == 0.0) continue;
      double tau = (Km[q][q] - Km[p][p]) / (2.0 * apq);
      double tt = (tau >= 0.0 ? 1.0 : -1.0) / (fabs(tau) + sqrt(1.0 + tau * tau));
      double cc = 1.0 / sqrt(1.0 + tt * tt), ss = tt * cc;
      for (int k = 0; k < 3; ++k) { double a1 = Km[p][k], a2 = Km[q][k]; Km[p][k] = cc * a1 - ss * a2; Km[q][k] = ss * a1 + cc * a2; }
      for (int k = 0; k < 3; ++k) { double a1 = Km[k][p], a2 = Km[k][q]; Km[k][p] = cc * a1 - ss * a2; Km[k][q] = ss * a1 + cc * a2; }
      for (int k = 0; k < 3; ++k) { double a1 = V[k][p], a2 = V[k][q]; V[k][p] = cc * a1 - ss * a2; V[k][q] = ss * a1 + cc * a2; }
    }
  }
  double lam[3] = {Km[0][0], Km[1][1], Km[2][2]};
  int o0 = 0, o1 = 1, o2 = 2; double detV = 1.0;
  if (lam[o0] < lam[o1]) { int t = o0; o0 = o1; o1 = t; detV = -detV; }
  if (lam[o1] < lam[o2]) { int t = o1; o1 = o2; o2 = t; detV = -detV; }
  if (lam[o0] < lam[o1]) { int t = o0; o0 = o1; o1 = t; detV = -detV; }
  double v0[3] = {V[0][o0], V[1][o0], V[2][o0]};
  double v1[3] = {V[0][o1], V[1][o1], V[2][o1]};
  double v2[3] = {V[0][o2], V[1][o2], V[2][o2]};
  double u0[3], u1[3];
  for (int i = 0; i < 3; ++i) u0[i] = m[i][0] * v0[0] + m[i][1] * v0[1] + m[i][2] * v0[2];
  double n0 = sqrt(u0[0] * u0[0] + u0[1] * u0[1] + u0[2] * u0[2]); if (n0 < 1e-30) n0 = 1e-30;
  for (int i = 0; i < 3; ++i) u0[i] /= n0;
  for (int i = 0; i < 3; ++i) u1[i] = m[i][0] * v1[0] + m[i][1] * v1[1] + m[i][2] * v1[2];
  double d01 = u0[0] * u1[0] + u0[1] * u1[1] + u0[2] * u1[2];
  for (int i = 0; i < 3; ++i) u1[i] -= d01 * u0[i];
  double n1 = sqrt(u1[0] * u1[0] + u1[1] * u1[1] + u1[2] * u1[2]); if (n1 < 1e-30) n1 = 1e-30;
  for (int i = 0; i < 3; ++i) u1[i] /= n1;
  double u2[3] = {u0[1] * u1[2] - u0[2] * u1[1],
                  u0[2] * u1[0] - u0[0] * u1[2],
                  u0[0] * u1[1] - u0[1] * u1[0]};
  float* o = out + (long)row * 16;
  for (int i = 0; i < 3; ++i) {
    for (int j = 0; j < 3; ++j)
      o[i * 4 + j] = (float)(u0[i] * v0[j] + u1[i] * v1[j] + detV * u2[i] * v2[j]);
    o[i * 4 + 3] = (float)t3[i];
  }
  o[12] = 0.f; o[13] = 0.f; o[14] = 0.f; o[15] = 1.f;
}

// ---------------------------------------------------------------------------
extern "C" void kernel_launch(void* const* d_in, const int* in_sizes, int n_in,
                              void* d_out, int out_size, void* d_ws, size_t ws_size,
                              hipStream_t stream) {
  (void)in_sizes; (void)n_in; (void)out_size; (void)ws_size;
  const float* feat   = (const float*)d_in[0];
  const float* W_res  = (const float*)d_in[5];
  const float* b_res  = (const float*)d_in[6];
  const float* W_cur1 = (const float*)d_in[7];
  const float* b_cur1 = (const float*)d_in[8];
  const float* W_cur2 = (const float*)d_in[9];
  const float* b_cur2 = (const float*)d_in[10];
  const float* W_tp1  = (const float*)d_in[11];
  const float* b_tp1  = (const float*)d_in[12];
  const float* W_tp2  = (const float*)d_in[13];
  const float* b_tp2  = (const float*)d_in[14];
  const float* W_fut1 = (const float*)d_in[15];
  const float* b_fut1 = (const float*)d_in[16];
  const float* W_fut2 = (const float*)d_in[17];
  const float* b_fut2 = (const float*)d_in[18];
  const float* W_m1   = (const float*)d_in[19];
  const float* b_m1   = (const float*)d_in[20];
  const float* W_m2   = (const float*)d_in[21];
  const float* b_m2   = (const float*)d_in[22];
  const float* W_t    = (const float*)d_in[23];
  const float* b_t    = (const float*)d_in[24];
  const float* W_r    = (const float*)d_in[25];
  const float* b_r    = (const float*)d_in[26];

  char* ws = (char*)d_ws;
  const size_t SZ_BIG = (size_t)R_PAD * DDIM * 2;  // 134,610,944 B each
  u16* A   = (u16*)(ws);                 // feat (bf16, padded) - updated in place
  u16* Bb  = (u16*)(ws + SZ_BIG);
  u16* Cb  = (u16*)(ws + 2 * SZ_BIG);
  u16* Wt6 = (u16*)(ws + 3 * SZ_BIG);    // 6x [512][512] bf16 transposed weights
  char* tail = ws + 3 * SZ_BIG + (size_t)6 * 512 * 512 * 2;
  float* pooled = (float*)(tail);            // [96][512]
  float* gctx   = pooled + 96 * 512;         // [32][512]
  float* tmp    = gctx + 32 * 512;           // [192][512] scratch
  float* tfb    = tmp + 192 * 512;           // [32][1536] == [96][512]
  float* allf   = tfb + 32 * 1536;           // [192][512]
  float* h2     = allf + 192 * 512;          // [192][512]
  float* outp   = (float*)d_out;

  convert_feat_k<<<65728, 256, 0, stream>>>(feat, A);
  transpose_w_k<<<6144, 256, 0, stream>>>(W_res, Wt6);

  const int NB = RT_GRID * 4;  // 4128 blocks (1D, XCD-remapped inside kernel)
  const size_t WS1 = (size_t)512 * 512;
  // ResConvBlock 0
  gemm_k<0><<<NB, 256, 0, stream>>>(A,  Wt6 + 0 * WS1, b_res + 0 * 512, nullptr, Bb);
  gemm_k<0><<<NB, 256, 0, stream>>>(Bb, Wt6 + 1 * WS1, b_res + 1 * 512, nullptr, Cb);
  gemm_k<1><<<NB, 256, 0, stream>>>(Cb, Wt6 + 2 * WS1, b_res + 2 * 512, A, A);
  // ResConvBlock 1
  gemm_k<0><<<NB, 256, 0, stream>>>(A,  Wt6 + 3 * WS1, b_res + 3 * 512, nullptr, Bb);
  gemm_k<0><<<NB, 256, 0, stream>>>(Bb, Wt6 + 4 * WS1, b_res + 4 * 512, nullptr, Cb);
  gemm_k<1><<<NB, 256, 0, stream>>>(Cb, Wt6 + 5 * WS1, b_res + 5 * 512, A, A);

  zero_k<<<(96 * 512 + 255) / 256, 256, 0, stream>>>(pooled, 96 * 512);
  pool_k<<<dim3(96, 8), 512, 0, stream>>>(A, pooled);
  gctx_k<<<(32 * 512 + 255) / 256, 256, 0, stream>>>(pooled, gctx);

  lin_k<true ><<<dim3(2, 96),  256, 0, stream>>>(pooled, W_cur1, b_cur1, tmp, 512, 512);
  lin_k<false><<<dim3(2, 96),  256, 0, stream>>>(tmp, W_cur2, b_cur2, allf, 512, 512);
  lin_k<true ><<<dim3(2, 32),  256, 0, stream>>>(gctx, W_tp1, b_tp1, tmp, 512, 512);
  lin_k<false><<<dim3(6, 32),  256, 0, stream>>>(tmp, W_tp2, b_tp2, tfb, 512, 1536);
  lin_k<true ><<<dim3(2, 96),  256, 0, stream>>>(tfb, W_fut1, b_fut1, tmp, 512, 512);
  lin_k<false><<<dim3(2, 96),  256, 0, stream>>>(tmp, W_fut2, b_fut2, allf + 96 * 512, 512, 512);
  lin_k<true ><<<dim3(2, 192), 256, 0, stream>>>(allf, W_m1, b_m1, tmp, 512, 512);
  lin_k<true ><<<dim3(2, 192), 256, 0, stream>>>(tmp, W_m2, b_m2, h2, 512, 512);

  pose_k<<<192, 64, 0, stream>>>(h2, W_t, b_t, W_r, b_r, outp);
}